// Round 3
// baseline (202.274 us; speedup 1.0000x reference)
//
#include <hip/hip_runtime.h>
#include <hip/hip_bf16.h>

// Workspace layout (needs 34 MB):
//   [0, 2MB)    Ut : U^T as bf16, Ut[n][k] = bf16(U[k][n])
//   [2MB, 34MB) xg : gathered x as bf16, xg[b][i] = bf16(x[b][ans[b][i]])
#define WS_UT    ((size_t)0)
#define WS_XG    ((size_t)2*1024*1024)

typedef __attribute__((ext_vector_type(8))) short short8;
typedef __attribute__((ext_vector_type(4))) float floatx4;

__device__ __forceinline__ void load_lds16(const void* g, void* l) {
  __builtin_amdgcn_global_load_lds(
      (const __attribute__((address_space(1))) void*)g,
      (__attribute__((address_space(3))) void*)l, 16, 0, 0);
}

__device__ __forceinline__ unsigned short f2bf(float f) {
  __hip_bfloat16 h = __float2bfloat16(f);
  return __builtin_bit_cast(unsigned short, h);
}
__device__ __forceinline__ float bf2f(unsigned short u) {
  return __uint_as_float(((unsigned)u) << 16);
}

// ---------------- K1: prep (Ut = bf16(U^T)) + gather (xg) in one launch ----------------
// blocks [0,256): transpose+cast U.  blocks [256, 256+4096): per-row LDS gather of x.
__global__ void __launch_bounds__(256) prep_gather_k(const float* __restrict__ U,
                                                     const float* __restrict__ x,
                                                     const int* __restrict__ perm,
                                                     const int* __restrict__ prand,
                                                     unsigned short* __restrict__ ut,
                                                     unsigned short* __restrict__ xg) {
  __shared__ __align__(16) char smem[64 * 65 * 4];  // union: tile[64][65] f32 / xrow[4][1024] f32
  if (blockIdx.x < 256) {
    float (*tile)[65] = (float (*)[65])smem;
    const int tn = (blockIdx.x & 15) * 64;
    const int tk = (blockIdx.x >> 4) * 64;
    const int r = threadIdx.x >> 6;
    const int c = threadIdx.x & 63;
    for (int s = 0; s < 16; ++s)
      tile[s * 4 + r][c] = U[(size_t)(tk + s * 4 + r) * 1024 + tn + c];
    __syncthreads();
    for (int s = 0; s < 16; ++s)
      ut[(size_t)(tn + s * 4 + r) * 1024 + tk + c] = f2bf(tile[c][s * 4 + r]);
    return;
  }
  float (*xrow)[1024] = (float (*)[1024])smem;
  const int w = threadIdx.x >> 6, lane = threadIdx.x & 63;
  const int row = (blockIdx.x - 256) * 4 + w;
  const unsigned mult = ((unsigned)prand[0] * 6u) & 1023u;
  const unsigned br = (((unsigned)row & 1023u) * mult + 1u) & 1023u;
  const float* xr = x + (size_t)row * 1024;
  unsigned short* xo = xg + (size_t)row * 1024;
  for (int t = 0; t < 4; ++t) {
    floatx4 v = *(const floatx4*)(xr + t * 256 + lane * 4);
    *(floatx4*)(&xrow[w][t * 256 + lane * 4]) = v;
  }
  __syncthreads();
  for (int t = 0; t < 4; ++t) {
    int i0 = t * 256 + lane * 4;
    int4 p = *(const int4*)(perm + i0);
    ushort4 o;
    o.x = f2bf(xrow[w][((unsigned)p.x * br) & 1023u]);
    o.y = f2bf(xrow[w][((unsigned)p.y * br) & 1023u]);
    o.z = f2bf(xrow[w][((unsigned)p.z * br) & 1023u]);
    o.w = f2bf(xrow[w][((unsigned)p.w * br) & 1023u]);
    *(ushort4*)(xo + i0) = o;
  }
}

// ---------------- K2: fused GEMM + scatter + residual ----------------
// Tile M=64 x N=1024 (full row), grid 256 (1 block/CU), 512 threads (8 waves).
// Round-3 changes (latency-bound fix; MfmaUtil was 13.5%, HBM 14%):
//  * B half-step software pipeline: while s=0 MFMAs consume bcur, the s=1
//    loads (bodd) are in flight, and vice versa. Issue->consume distance
//    ~32 MFMA >= L2 latency. Zero extra register state (sets rotate).
//  * A-ring of 4 LDS buffers, staged 2 k-steps ahead (~1300 cyc >= HBM lat).
//  * RAW s_barrier (sched_barrier-fenced) instead of __syncthreads in the
//    main loop: no vmcnt(0) drain. Correctness by in-order vmcnt retirement:
//    each wave's compiler-emitted wait for bodd(kt) — issued AFTER its own
//    A(kt+1) stage (previous body, behind a sched fence) — drains that stage
//    before the barrier. So no wave crosses the barrier with its staging
//    incomplete, and no explicit drain is needed.
//  * Prologue/epilogue keep full __syncthreads().
__global__ void __launch_bounds__(512, 1) gemm_scatter_k(
    const unsigned short* __restrict__ xg,
    const unsigned short* __restrict__ ut,
    const int* __restrict__ perm,
    const int* __restrict__ prand,
    float* __restrict__ out) {
  // [0,32KB): A ring buffer (4 x [64 rows][64 k] bf16, swizzled)
  // epilogue reuse: sbuf[16][1024] f32 = 64KB
  __shared__ __align__(16) char smem[65536];
  const int tid = threadIdx.x;
  const int w = tid >> 6, lane = tid & 63;
  const int m = lane & 15, q = lane >> 4;
  const int R0 = blockIdx.x * 64;
  const int wn = w * 128;

  // A-read swizzle: chunk slot = (s*4+q) ^ (m&7), split per-lane per s
  const int x3 = m & 7;
  const int qq = q ^ (x3 & 3);
  const int sf = x3 >> 2;
  const int offA0 = m * 128 + (qq + sf * 4) * 16;        // s=0
  const int offA1 = m * 128 + (qq + 4 - sf * 4) * 16;    // s=1

  // A staging: each thread stages one 16B chunk per buffer.
  // LDS row = w*8 + (lane>>3), slot = lane&7 (dest = base + lane*16, linear)
  // global chunk = slot ^ (row&7) (inverse-swizzled source)
  const int sr = lane >> 3, sslot = lane & 7;
  const unsigned short* asrc =
      xg + (size_t)(R0 + w * 8 + sr) * 1024 + (size_t)((sslot ^ sr) * 8);
  char* adst0 = smem + w * 1024 + lane * 16;

  // B base pointers: col = wn + jj*16 + m fixed per jj; per-lane k-chunk q*8.
  const unsigned short* bb[8];
#pragma unroll
  for (int jj = 0; jj < 8; ++jj)
    bb[jj] = ut + (size_t)(wn + jj * 16 + m) * 1024 + q * 8;

  floatx4 acc[4][8];
#pragma unroll
  for (int i = 0; i < 4; ++i)
#pragma unroll
    for (int jj = 0; jj < 8; ++jj) acc[i][jj] = (floatx4)0.0f;

  // ---- prologue: stage A(0)->buf0, A(1)->buf1; preload B(0,s=0); full sync
  load_lds16(asrc, adst0);
  load_lds16(asrc + 64, adst0 + 8192);
  short8 bcur[8];
#pragma unroll
  for (int jj = 0; jj < 8; ++jj) bcur[jj] = *(const short8*)(bb[jj]);
  __syncthreads();

#pragma unroll
  for (int kt = 0; kt < 16; ++kt) {
    const char* Ac = smem + (kt & 3) * 8192;
    // ---- half 0: issue (kt,s=1) B loads; compute with bcur = (kt,s=0) ----
    short8 bodd[8];
#pragma unroll
    for (int jj = 0; jj < 8; ++jj)
      bodd[jj] = *(const short8*)(bb[jj] + kt * 64 + 32);
    short8 a0[4];
#pragma unroll
    for (int i = 0; i < 4; ++i) a0[i] = *(const short8*)(Ac + i * 2048 + offA0);
#pragma unroll
    for (int i = 0; i < 4; ++i)
#pragma unroll
      for (int jj = 0; jj < 8; ++jj)
        acc[i][jj] = __builtin_amdgcn_mfma_f32_16x16x32_bf16(bcur[jj], a0[i],
                                                             acc[i][jj], 0, 0, 0);
    // ---- half 1: issue (kt+1,s=0) B loads + stage A(kt+2); compute bodd ----
    if (kt < 15) {
#pragma unroll
      for (int jj = 0; jj < 8; ++jj)
        bcur[jj] = *(const short8*)(bb[jj] + (kt + 1) * 64);
    }
    if (kt < 14)
      load_lds16(asrc + (size_t)(kt + 2) * 64, adst0 + ((kt + 2) & 3) * 8192);
    short8 a1[4];
#pragma unroll
    for (int i = 0; i < 4; ++i) a1[i] = *(const short8*)(Ac + i * 2048 + offA1);
#pragma unroll
    for (int i = 0; i < 4; ++i)
#pragma unroll
      for (int jj = 0; jj < 8; ++jj)
        acc[i][jj] = __builtin_amdgcn_mfma_f32_16x16x32_bf16(bodd[jj], a1[i],
                                                             acc[i][jj], 0, 0, 0);
    if (kt < 15) {
      // raw barrier, no vmcnt drain (see header comment for the safety arg)
      __builtin_amdgcn_sched_barrier(0);
      __builtin_amdgcn_s_barrier();
      __builtin_amdgcn_sched_barrier(0);
    }
  }
  __syncthreads();  // full drain before sbuf overwrites the A ring

  // ---- epilogue: 4 passes of 16 rows; value = s*y + xg scattered via LDS ----
  // FULLY UNROLLED: acc indices must be compile-time constants (rule #20).
  const unsigned mult = ((unsigned)prand[0] * 6u) & 1023u;
  const float rs = 0.33333334f;  // sqrt(0.1/0.9) = 1/3
  float* sbuf = (float*)smem;    // [16][1024] f32
#pragma unroll
  for (int i = 0; i < 4; ++i) {
    const int row = R0 + i * 16 + m;  // lane's y-row (swapped-mfma layout)
    const unsigned br = (((unsigned)row & 1023u) * mult + 1u) & 1023u;
    const unsigned short* xr = xg + (size_t)row * 1024;
#pragma unroll
    for (int jj = 0; jj < 8; ++jj) {
      const int j0 = wn + jj * 16 + q * 4;  // 4 consecutive y-cols per lane
      const int4 p4 = *(const int4*)(perm + j0);
      const ushort4 x4 = *(const ushort4*)(xr + j0);  // L2-hot (block's A panel)
      sbuf[m * 1024 + (((unsigned)p4.x * br) & 1023u)] = rs * acc[i][jj][0] + bf2f(x4.x);
      sbuf[m * 1024 + (((unsigned)p4.y * br) & 1023u)] = rs * acc[i][jj][1] + bf2f(x4.y);
      sbuf[m * 1024 + (((unsigned)p4.z * br) & 1023u)] = rs * acc[i][jj][2] + bf2f(x4.z);
      sbuf[m * 1024 + (((unsigned)p4.w * br) & 1023u)] = rs * acc[i][jj][3] + bf2f(x4.w);
    }
    __syncthreads();
    float* orow0 = out + (size_t)(R0 + i * 16) * 1024;
#pragma unroll
    for (int v = 0; v < 8; ++v) {
      const int f = v * 512 + tid;  // float4 index in [0,4096)
      *(floatx4*)(orow0 + ((f >> 8) * 1024 + (f & 255) * 4)) =
          *(const floatx4*)(sbuf + (size_t)f * 4);
    }
    if (i < 3) __syncthreads();
  }
}

extern "C" void kernel_launch(void* const* d_in, const int* in_sizes, int n_in,
                              void* d_out, int out_size, void* d_ws, size_t ws_size,
                              hipStream_t stream) {
  const float* x = (const float*)d_in[0];
  const float* U = (const float*)d_in[1];
  const int* perm = (const int*)d_in[2];
  const int* prand = (const int*)d_in[3];
  float* out = (float*)d_out;
  char* ws = (char*)d_ws;
  unsigned short* ut = (unsigned short*)(ws + WS_UT);
  unsigned short* xg = (unsigned short*)(ws + WS_XG);

  prep_gather_k<<<256 + 4096, 256, 0, stream>>>(U, x, perm, prand, ut, xg);
  gemm_scatter_k<<<256, 512, 0, stream>>>(xg, ut, perm, prand, out);
}

// Round 4
// 171.997 us; speedup vs baseline: 1.1760x; 1.1760x over previous
//
#include <hip/hip_runtime.h>
#include <hip/hip_bf16.h>

// Workspace layout (needs 34 MB):
//   [0, 2MB)    Ut : U^T as bf16, Ut[n][k] = bf16(U[k][n])
//   [2MB, 34MB) xg : gathered x as bf16, xg[b][i] = bf16(x[b][ans[b][i]])
#define WS_UT    ((size_t)0)
#define WS_XG    ((size_t)2*1024*1024)

typedef __attribute__((ext_vector_type(8))) short short8;
typedef __attribute__((ext_vector_type(4))) float floatx4;

__device__ __forceinline__ void load_lds16(const void* g, void* l) {
  __builtin_amdgcn_global_load_lds(
      (const __attribute__((address_space(1))) void*)g,
      (__attribute__((address_space(3))) void*)l, 16, 0, 0);
}

__device__ __forceinline__ unsigned short f2bf(float f) {
  __hip_bfloat16 h = __float2bfloat16(f);
  return __builtin_bit_cast(unsigned short, h);
}
__device__ __forceinline__ float bf2f(unsigned short u) {
  return __uint_as_float(((unsigned)u) << 16);
}

// ---------------- K1: prep (Ut = bf16(U^T)) + gather (xg) in one launch ----------------
// blocks [0,256): transpose+cast U.  blocks [256, 256+4096): per-row LDS gather of x.
__global__ void __launch_bounds__(256) prep_gather_k(const float* __restrict__ U,
                                                     const float* __restrict__ x,
                                                     const int* __restrict__ perm,
                                                     const int* __restrict__ prand,
                                                     unsigned short* __restrict__ ut,
                                                     unsigned short* __restrict__ xg) {
  __shared__ __align__(16) char smem[64 * 65 * 4];  // union: tile[64][65] f32 / xrow[4][1024] f32
  if (blockIdx.x < 256) {
    float (*tile)[65] = (float (*)[65])smem;
    const int tn = (blockIdx.x & 15) * 64;
    const int tk = (blockIdx.x >> 4) * 64;
    const int r = threadIdx.x >> 6;
    const int c = threadIdx.x & 63;
    for (int s = 0; s < 16; ++s)
      tile[s * 4 + r][c] = U[(size_t)(tk + s * 4 + r) * 1024 + tn + c];
    __syncthreads();
    for (int s = 0; s < 16; ++s)
      ut[(size_t)(tn + s * 4 + r) * 1024 + tk + c] = f2bf(tile[c][s * 4 + r]);
    return;
  }
  float (*xrow)[1024] = (float (*)[1024])smem;
  const int w = threadIdx.x >> 6, lane = threadIdx.x & 63;
  const int row = (blockIdx.x - 256) * 4 + w;
  const unsigned mult = ((unsigned)prand[0] * 6u) & 1023u;
  const unsigned br = (((unsigned)row & 1023u) * mult + 1u) & 1023u;
  const float* xr = x + (size_t)row * 1024;
  unsigned short* xo = xg + (size_t)row * 1024;
  for (int t = 0; t < 4; ++t) {
    floatx4 v = *(const floatx4*)(xr + t * 256 + lane * 4);
    *(floatx4*)(&xrow[w][t * 256 + lane * 4]) = v;
  }
  __syncthreads();
  for (int t = 0; t < 4; ++t) {
    int i0 = t * 256 + lane * 4;
    int4 p = *(const int4*)(perm + i0);
    ushort4 o;
    o.x = f2bf(xrow[w][((unsigned)p.x * br) & 1023u]);
    o.y = f2bf(xrow[w][((unsigned)p.y * br) & 1023u]);
    o.z = f2bf(xrow[w][((unsigned)p.z * br) & 1023u]);
    o.w = f2bf(xrow[w][((unsigned)p.w * br) & 1023u]);
    *(ushort4*)(xo + i0) = o;
  }
}

// ---------------- K2: fused GEMM + scatter + residual ----------------
// Tile M=64 x N=1024 (full row), grid 256 (1 block/CU), 512 threads (8 waves,
// wave w owns cols [w*128, w*128+128)).
// Round-4 change (VGPR-ceiling fix): B now goes through LDS via
// global_load_lds instead of L2->VGPR streaming. Rounds 2 & 3 were identical
// at 95us / MfmaUtil 13.5% despite different schedules because the 8-wave
// block (2 waves/SIMD -> <=256 regs/wave) with 128 AGPR acc hard-caps arch
// VGPRs at 128 -- B-in-register state (~130 live) left the scheduler zero
// slack, so loads serialized at ~700cy each (16 steps x 17 vmem x 700cy ~=
// 95us, matching). global_load_lds has NO VGPR destination; B fragments are
// transient ds_read_b128 right before their MFMAs -> live arch demand ~80.
//  * LDS: A[64x64] 8KB + B[1024x64] 128KB = 136KB single-buffered (dynamic
//    LDS, hipFuncSetAttribute). 1 block/CU. Epilogue sbuf reuses [0,64KB).
//  * Both tiles XOR-swizzled: linear load_lds dest + inverse-swizzled global
//    source; read slot = (s*4+q)^(m&7) is bijective per 8-lane group ->
//    conflict-free ds_read_b128.
//  * Per k-step: stage A (1 instr) + B (16 instr) -> __syncthreads (vmcnt(0)
//    drain, required anyway for single buffer) -> 2x(12 ds_read + 32 MFMA)
//    -> __syncthreads.
__global__ void __launch_bounds__(512, 1) gemm_scatter_k(
    const unsigned short* __restrict__ xg,
    const unsigned short* __restrict__ ut,
    const int* __restrict__ perm,
    const int* __restrict__ prand,
    float* __restrict__ out) {
  extern __shared__ __align__(16) char smem[];
  char* Abuf = smem;          // [64 rows][64 k] bf16, rows 128B, swizzled
  char* Bbuf = smem + 8192;   // [1024 rows][64 k] bf16, rows 128B, swizzled
  const int tid = threadIdx.x;
  const int w = tid >> 6, lane = tid & 63;
  const int m = lane & 15, q = lane >> 4;
  const int R0 = blockIdx.x * 64;
  const int wn = w * 128;

  // fragment-read swizzle: slot = (s*4+q) ^ (m&7), bijective per 8 lanes
  const int x3 = m & 7;
  const int qq = q ^ (x3 & 3);
  const int sf = x3 >> 2;
  const int offF0 = m * 128 + (qq + sf * 4) * 16;        // s=0
  const int offF1 = m * 128 + (qq + 4 - sf * 4) * 16;    // s=1

  // staging: each instr covers 8 rows x 8 slots; row=lane>>3, slot=lane&7
  // dest = base + lane*16 (linear); global chunk = slot ^ (row&7)
  const int sr = lane >> 3, sslot = lane & 7;
  const unsigned short* asrc =
      xg + (size_t)(R0 + w * 8 + sr) * 1024 + (size_t)((sslot ^ sr) * 8);
  char* adst = Abuf + w * 1024 + lane * 16;
  // B: wave w stages rows [w*128, w*128+128): 16 instrs of 8 rows
  const unsigned short* bsrc =
      ut + (size_t)(w * 128 + sr) * 1024 + (size_t)((sslot ^ sr) * 8);
  char* bdst = Bbuf + w * 16384 + lane * 16;

  floatx4 acc[4][8];
#pragma unroll
  for (int i = 0; i < 4; ++i)
#pragma unroll
    for (int jj = 0; jj < 8; ++jj) acc[i][jj] = (floatx4)0.0f;

#pragma unroll 1
  for (int kt = 0; kt < 16; ++kt) {
    const int k0 = kt * 64;
    load_lds16(asrc + k0, adst);
#pragma unroll
    for (int t = 0; t < 16; ++t)
      load_lds16(bsrc + (size_t)t * 8192 + k0, bdst + t * 1024);
    __syncthreads();  // drains this step's stages (vmcnt(0)) + aligns waves
    // ---- s=0 half (k elements [k0, k0+32)) ----
    short8 a0[4], b0[8];
#pragma unroll
    for (int i = 0; i < 4; ++i) a0[i] = *(const short8*)(Abuf + i * 2048 + offF0);
#pragma unroll
    for (int jj = 0; jj < 8; ++jj)
      b0[jj] = *(const short8*)(Bbuf + wn * 128 + jj * 2048 + offF0);
#pragma unroll
    for (int i = 0; i < 4; ++i)
#pragma unroll
      for (int jj = 0; jj < 8; ++jj)
        acc[i][jj] = __builtin_amdgcn_mfma_f32_16x16x32_bf16(b0[jj], a0[i],
                                                             acc[i][jj], 0, 0, 0);
    // ---- s=1 half (k elements [k0+32, k0+64)) ----
    short8 a1[4], b1[8];
#pragma unroll
    for (int i = 0; i < 4; ++i) a1[i] = *(const short8*)(Abuf + i * 2048 + offF1);
#pragma unroll
    for (int jj = 0; jj < 8; ++jj)
      b1[jj] = *(const short8*)(Bbuf + wn * 128 + jj * 2048 + offF1);
#pragma unroll
    for (int i = 0; i < 4; ++i)
#pragma unroll
      for (int jj = 0; jj < 8; ++jj)
        acc[i][jj] = __builtin_amdgcn_mfma_f32_16x16x32_bf16(b1[jj], a1[i],
                                                             acc[i][jj], 0, 0, 0);
    __syncthreads();  // all waves done reading before next step overwrites
  }

  // ---- epilogue: 4 passes of 16 rows; value = s*y + xg scattered via LDS ----
  // FULLY UNROLLED: acc indices must be compile-time constants (rule #20).
  const unsigned mult = ((unsigned)prand[0] * 6u) & 1023u;
  const float rs = 0.33333334f;  // sqrt(0.1/0.9) = 1/3
  float* sbuf = (float*)smem;    // [16][1024] f32 (reuses A+B region)
#pragma unroll
  for (int i = 0; i < 4; ++i) {
    const int row = R0 + i * 16 + m;  // lane's y-row (swapped-mfma layout)
    const unsigned br = (((unsigned)row & 1023u) * mult + 1u) & 1023u;
    const unsigned short* xr = xg + (size_t)row * 1024;
#pragma unroll
    for (int jj = 0; jj < 8; ++jj) {
      const int j0 = wn + jj * 16 + q * 4;  // 4 consecutive y-cols per lane
      const int4 p4 = *(const int4*)(perm + j0);
      const ushort4 x4 = *(const ushort4*)(xr + j0);  // L2-hot (block's A panel)
      sbuf[m * 1024 + (((unsigned)p4.x * br) & 1023u)] = rs * acc[i][jj][0] + bf2f(x4.x);
      sbuf[m * 1024 + (((unsigned)p4.y * br) & 1023u)] = rs * acc[i][jj][1] + bf2f(x4.y);
      sbuf[m * 1024 + (((unsigned)p4.z * br) & 1023u)] = rs * acc[i][jj][2] + bf2f(x4.z);
      sbuf[m * 1024 + (((unsigned)p4.w * br) & 1023u)] = rs * acc[i][jj][3] + bf2f(x4.w);
    }
    __syncthreads();
    float* orow0 = out + (size_t)(R0 + i * 16) * 1024;
#pragma unroll
    for (int v = 0; v < 8; ++v) {
      const int f = v * 512 + tid;  // float4 index in [0,4096)
      *(floatx4*)(orow0 + ((f >> 8) * 1024 + (f & 255) * 4)) =
          *(const floatx4*)(sbuf + (size_t)f * 4);
    }
    if (i < 3) __syncthreads();
  }
}

extern "C" void kernel_launch(void* const* d_in, const int* in_sizes, int n_in,
                              void* d_out, int out_size, void* d_ws, size_t ws_size,
                              hipStream_t stream) {
  const float* x = (const float*)d_in[0];
  const float* U = (const float*)d_in[1];
  const int* perm = (const int*)d_in[2];
  const int* prand = (const int*)d_in[3];
  float* out = (float*)d_out;
  char* ws = (char*)d_ws;
  unsigned short* ut = (unsigned short*)(ws + WS_UT);
  unsigned short* xg = (unsigned short*)(ws + WS_XG);

  // 136KB dynamic LDS for K2 (above the 64KB default cap)
  hipFuncSetAttribute((const void*)gemm_scatter_k,
                      hipFuncAttributeMaxDynamicSharedMemorySize, 139264);

  prep_gather_k<<<256 + 4096, 256, 0, stream>>>(U, x, perm, prand, ut, xg);
  gemm_scatter_k<<<256, 512, 139264, stream>>>(xg, ut, perm, prand, out);
}